// Round 1
// baseline (554.867 us; speedup 1.0000x reference)
//
#include <hip/hip_runtime.h>
#include <hip/hip_bf16.h>

#define BB 8
#define CC 4096
#define DD 1024
#define EE 16
#define ESS 256
#define KSEL 4096
#define NTOK (BB*CC)

typedef short bf16x8 __attribute__((ext_vector_type(8)));
typedef float f32x4 __attribute__((ext_vector_type(4)));

__device__ __forceinline__ short f2bf(float f) {
  unsigned u = __float_as_uint(f);
  u += 0x7FFFu + ((u >> 16) & 1u);
  return (short)(u >> 16);
}

// ---------------- K1: xsum + logits ----------------
// one wave per token; logits[e][t] = (sum_d x[t][d]) * gate[c][e]
__global__ void k_logits(const float* __restrict__ x, const float* __restrict__ gate,
                         float* __restrict__ logits) {
  int wid = threadIdx.x >> 6, lane = threadIdx.x & 63;
  int t = blockIdx.x * 4 + wid;
  const float4* xr = reinterpret_cast<const float4*>(x + (size_t)t * DD);
  float s = 0.f;
#pragma unroll
  for (int i = 0; i < 4; ++i) {
    float4 v = xr[lane + 64 * i];
    s += v.x + v.y + v.z + v.w;
  }
#pragma unroll
  for (int off = 32; off; off >>= 1) s += __shfl_xor(s, off);
  if (lane < EE) {
    int c = t & (CC - 1);
    logits[(size_t)lane * NTOK + t] = s * gate[c * EE + lane];
  }
}

// ---------------- K2: per-expert max + sumexp ----------------
__global__ void k_stats(const float* __restrict__ logits, float* __restrict__ smax,
                        float* __restrict__ ssum) {
  int e = blockIdx.x;
  const float* L = logits + (size_t)e * NTOK;
  __shared__ float red[256];
  float m = -3.4e38f;
  for (int t = threadIdx.x; t < NTOK; t += 256) m = fmaxf(m, L[t]);
  red[threadIdx.x] = m; __syncthreads();
  for (int s2 = 128; s2; s2 >>= 1) {
    if (threadIdx.x < s2) red[threadIdx.x] = fmaxf(red[threadIdx.x], red[threadIdx.x + s2]);
    __syncthreads();
  }
  m = red[0]; __syncthreads();
  float s = 0.f;
  for (int t = threadIdx.x; t < NTOK; t += 256) s += expf(L[t] - m);
  red[threadIdx.x] = s; __syncthreads();
  for (int s2 = 128; s2; s2 >>= 1) {
    if (threadIdx.x < s2) red[threadIdx.x] += red[threadIdx.x + s2];
    __syncthreads();
  }
  if (threadIdx.x == 0) { smax[e] = m; ssum[e] = red[0]; }
}

// ---------------- K3: radix top-k select + ordered compaction ----------------
__global__ void k_select(const float* __restrict__ logits, const float* __restrict__ smax,
                         const float* __restrict__ ssum, int* __restrict__ sel_idx,
                         float* __restrict__ sel_val) {
  int e = blockIdx.x;
  const float* L = logits + (size_t)e * NTOK;
  __shared__ unsigned hist[256];
  __shared__ unsigned sh_prefix, sh_kth, sh_ngt;
  __shared__ unsigned wtg[4], wtq[4];
  __shared__ unsigned base_gt, base_eq;

  unsigned prefix = 0, kth = KSEL, n_gt = 0;
  for (int pass = 3; pass >= 0; --pass) {
    hist[threadIdx.x] = 0;
    __syncthreads();
    unsigned shift = pass * 8;
    unsigned pmask = (pass == 3) ? 0u : (0xFFFFFFFFu << ((pass + 1) * 8));
    for (int t = threadIdx.x; t < NTOK; t += 256) {
      unsigned u = __float_as_uint(L[t]);
      unsigned key = (u & 0x80000000u) ? ~u : (u | 0x80000000u);
      if ((key & pmask) == prefix) atomicAdd(&hist[(key >> shift) & 255], 1u);
    }
    __syncthreads();
    if (threadIdx.x == 0) {
      unsigned cum = 0; int d = 255;
      for (; d >= 0; --d) {
        if (cum + hist[d] >= kth) break;
        cum += hist[d];
      }
      sh_ngt = n_gt + cum;
      sh_kth = kth - cum;
      sh_prefix = prefix | ((unsigned)d << shift);
    }
    __syncthreads();
    prefix = sh_prefix; kth = sh_kth; n_gt = sh_ngt;
    __syncthreads();
  }
  unsigned tau = prefix;
  unsigned n_tie = KSEL - n_gt;
  float mx = smax[e], sm = ssum[e];

  if (threadIdx.x == 0) { base_gt = 0; base_eq = 0; }
  __syncthreads();
  int wid = threadIdx.x >> 6, lane = threadIdx.x & 63;
  for (int t0 = 0; t0 < NTOK; t0 += 256) {
    int t = t0 + threadIdx.x;
    float lv = L[t];
    unsigned u = __float_as_uint(lv);
    unsigned key = (u & 0x80000000u) ? ~u : (u | 0x80000000u);
    bool g = key > tau, q = key == tau;
    unsigned long long bg = __ballot(g), bq = __ballot(q);
    unsigned long long lm = (1ull << lane) - 1ull;
    unsigned pg = __popcll(bg & lm), pq = __popcll(bq & lm);
    if (lane == 63) { wtg[wid] = pg + (g ? 1u : 0u); wtq[wid] = pq + (q ? 1u : 0u); }
    __syncthreads();
    unsigned og = base_gt, oq = base_eq;
    for (int w2 = 0; w2 < wid; ++w2) { og += wtg[w2]; oq += wtq[w2]; }
    if (g) {
      unsigned slot = og + pg;
      sel_idx[(size_t)e * KSEL + slot] = t;
      sel_val[(size_t)e * KSEL + slot] = expf(lv - mx) / sm;
    } else if (q) {
      unsigned r = oq + pq;
      if (r < n_tie) {
        unsigned slot = n_gt + r;
        sel_idx[(size_t)e * KSEL + slot] = t;
        sel_val[(size_t)e * KSEL + slot] = expf(lv - mx) / sm;
      }
    }
    __syncthreads();
    if (threadIdx.x == 0) {
      base_gt += wtg[0] + wtg[1] + wtg[2] + wtg[3];
      base_eq += wtq[0] + wtq[1] + wtq[2] + wtq[3];
    }
    __syncthreads();
  }
}

// ---------------- transpose: src [batch][R][C] f32 -> dst [batch][C][R] bf16 ----------------
__global__ void k_transpose(const float* __restrict__ src, short* __restrict__ dst,
                            int R, int C) {
  __shared__ float tile[64][65];
  int c0 = blockIdx.x * 64, r0 = blockIdx.y * 64, b = blockIdx.z;
  const float* S = src + (size_t)b * R * C;
  short* Dp = dst + (size_t)b * R * C;
  int tx = threadIdx.x & 63, ty = threadIdx.x >> 6;
#pragma unroll
  for (int i = 0; i < 16; ++i) {
    int r = ty + 4 * i;
    tile[r][tx] = S[(size_t)(r0 + r) * C + c0 + tx];
  }
  __syncthreads();
#pragma unroll
  for (int i = 0; i < 16; ++i) {
    int cR = ty + 4 * i;
    Dp[(size_t)(c0 + cR) * R + r0 + tx] = f2bf(tile[tx][cR]);
  }
}

// ---------------- GEMM1: H[e][m][s] = bf16( relu( Xg[e] @ W1[e] ) * val[e][m] ) ----------------
// BM=128 BN=256 BK=64, 4 waves in 2x2, 16x16x32 bf16 MFMA, XOR-swizzled LDS (seg^row&7)
__global__ __launch_bounds__(256, 2) void k_gemm1(
    const float* __restrict__ x, const short* __restrict__ W1T,
    const int* __restrict__ sel_idx, const float* __restrict__ sel_val,
    short* __restrict__ H) {
  int e = blockIdx.y, m0 = blockIdx.x * 128;
  __shared__ bf16x8 As8[128 * 8];   // 16 KB
  __shared__ bf16x8 Bs8[256 * 8];   // 32 KB
  int tid = threadIdx.x, lane = tid & 63, wid = tid >> 6;
  int wr = wid >> 1, wc = wid & 1;
  const int* idxE = sel_idx + (size_t)e * KSEL;
  f32x4 acc[4][8] = {};

  int ar = tid >> 1, ah = tid & 1;
  int tokenA = idxE[m0 + ar];
  const float* aSrc = x + (size_t)tokenA * DD + ah * 32;

  for (int kt = 0; kt < DD / 64; ++kt) {
    // stage A (gather + fp32->bf16)
    {
      const float4* s4 = reinterpret_cast<const float4*>(aSrc + kt * 64);
#pragma unroll
      for (int j = 0; j < 4; ++j) {
        float4 v0 = s4[2 * j], v1 = s4[2 * j + 1];
        bf16x8 pk;
        pk[0] = f2bf(v0.x); pk[1] = f2bf(v0.y); pk[2] = f2bf(v0.z); pk[3] = f2bf(v0.w);
        pk[4] = f2bf(v1.x); pk[5] = f2bf(v1.y); pk[6] = f2bf(v1.z); pk[7] = f2bf(v1.w);
        As8[ar * 8 + ((ah * 4 + j) ^ (ar & 7))] = pk;
      }
    }
    // stage B (bf16 direct copy from pre-transposed W1T[e][s][d])
    {
#pragma unroll
      for (int j = 0; j < 8; ++j) {
        int seg_id = tid + 256 * j;
        int row = seg_id >> 3, s8 = seg_id & 7;
        uint4 v = *reinterpret_cast<const uint4*>(W1T + ((size_t)(e * ESS + row) * DD + kt * 64) + s8 * 8);
        reinterpret_cast<uint4*>(Bs8)[row * 8 + (s8 ^ (row & 7))] = v;
      }
    }
    __syncthreads();
    bf16x8 af[4][2];
#pragma unroll
    for (int mg = 0; mg < 4; ++mg)
#pragma unroll
      for (int h = 0; h < 2; ++h) {
        int row = wr * 64 + mg * 16 + (lane & 15);
        int seg = h * 4 + (lane >> 4);
        af[mg][h] = As8[row * 8 + (seg ^ (row & 7))];
      }
#pragma unroll
    for (int ng = 0; ng < 8; ++ng) {
      bf16x8 bfr[2];
#pragma unroll
      for (int h = 0; h < 2; ++h) {
        int row = wc * 128 + ng * 16 + (lane & 15);
        int seg = h * 4 + (lane >> 4);
        bfr[h] = Bs8[row * 8 + (seg ^ (row & 7))];
      }
#pragma unroll
      for (int mg = 0; mg < 4; ++mg) {
        acc[mg][ng] = __builtin_amdgcn_mfma_f32_16x16x32_bf16(af[mg][0], bfr[0], acc[mg][ng], 0, 0, 0);
        acc[mg][ng] = __builtin_amdgcn_mfma_f32_16x16x32_bf16(af[mg][1], bfr[1], acc[mg][ng], 0, 0, 0);
      }
    }
    __syncthreads();
  }
  // epilogue: relu, scale by gate prob, store bf16
#pragma unroll
  for (int mg = 0; mg < 4; ++mg) {
#pragma unroll
    for (int r = 0; r < 4; ++r) {
      int ml = wr * 64 + mg * 16 + (lane >> 4) * 4 + r;
      float v = sel_val[(size_t)e * KSEL + m0 + ml];
#pragma unroll
      for (int ng = 0; ng < 8; ++ng) {
        float o = fmaxf(acc[mg][ng][r], 0.f) * v;
        H[((size_t)(e * KSEL + m0 + ml)) * ESS + wc * 128 + ng * 16 + (lane & 15)] = f2bf(o);
      }
    }
  }
}

// ---------------- GEMM2: z[token] += H[e] @ W2[e] (atomic scatter) ----------------
__global__ __launch_bounds__(256, 2) void k_gemm2(
    const short* __restrict__ H, const short* __restrict__ W2T,
    const int* __restrict__ sel_idx, float* __restrict__ z) {
  int e = blockIdx.z, m0 = blockIdx.x * 128, n0 = blockIdx.y * 256;
  __shared__ bf16x8 As8[128 * 8];
  __shared__ bf16x8 Bs8[256 * 8];
  int tid = threadIdx.x, lane = tid & 63, wid = tid >> 6;
  int wr = wid >> 1, wc = wid & 1;
  f32x4 acc[4][8] = {};

  for (int kt = 0; kt < ESS / 64; ++kt) {
    // stage A from H[e][m][s]
#pragma unroll
    for (int j = 0; j < 4; ++j) {
      int seg_id = tid + 256 * j;
      int row = seg_id >> 3, s8 = seg_id & 7;
      uint4 v = *reinterpret_cast<const uint4*>(H + ((size_t)(e * KSEL + m0 + row) * ESS + kt * 64) + s8 * 8);
      reinterpret_cast<uint4*>(As8)[row * 8 + (s8 ^ (row & 7))] = v;
    }
    // stage B from W2T[e][n][s]
#pragma unroll
    for (int j = 0; j < 8; ++j) {
      int seg_id = tid + 256 * j;
      int row = seg_id >> 3, s8 = seg_id & 7;
      uint4 v = *reinterpret_cast<const uint4*>(W2T + ((size_t)(e * DD + n0 + row) * ESS + kt * 64) + s8 * 8);
      reinterpret_cast<uint4*>(Bs8)[row * 8 + (s8 ^ (row & 7))] = v;
    }
    __syncthreads();
    bf16x8 af[4][2];
#pragma unroll
    for (int mg = 0; mg < 4; ++mg)
#pragma unroll
      for (int h = 0; h < 2; ++h) {
        int row = wr * 64 + mg * 16 + (lane & 15);
        int seg = h * 4 + (lane >> 4);
        af[mg][h] = As8[row * 8 + (seg ^ (row & 7))];
      }
#pragma unroll
    for (int ng = 0; ng < 8; ++ng) {
      bf16x8 bfr[2];
#pragma unroll
      for (int h = 0; h < 2; ++h) {
        int row = wc * 128 + ng * 16 + (lane & 15);
        int seg = h * 4 + (lane >> 4);
        bfr[h] = Bs8[row * 8 + (seg ^ (row & 7))];
      }
#pragma unroll
      for (int mg = 0; mg < 4; ++mg) {
        acc[mg][ng] = __builtin_amdgcn_mfma_f32_16x16x32_bf16(af[mg][0], bfr[0], acc[mg][ng], 0, 0, 0);
        acc[mg][ng] = __builtin_amdgcn_mfma_f32_16x16x32_bf16(af[mg][1], bfr[1], acc[mg][ng], 0, 0, 0);
      }
    }
    __syncthreads();
  }
  // epilogue: atomic scatter-add into z
#pragma unroll
  for (int mg = 0; mg < 4; ++mg) {
#pragma unroll
    for (int r = 0; r < 4; ++r) {
      int ml = wr * 64 + mg * 16 + (lane >> 4) * 4 + r;
      int token = sel_idx[(size_t)e * KSEL + m0 + ml];
      float* zr = z + (size_t)token * DD + n0 + wc * 128 + (lane & 15);
#pragma unroll
      for (int ng = 0; ng < 8; ++ng) atomicAdd(zr + ng * 16, acc[mg][ng][r]);
    }
  }
}

extern "C" void kernel_launch(void* const* d_in, const int* in_sizes, int n_in,
                              void* d_out, int out_size, void* d_ws, size_t ws_size,
                              hipStream_t stream) {
  (void)in_sizes; (void)n_in; (void)ws_size;
  const float* x = (const float*)d_in[0];
  const float* gate = (const float*)d_in[1];
  const float* lin1 = (const float*)d_in[2];
  const float* lin2 = (const float*)d_in[3];
  float* z = (float*)d_out;

  char* ws = (char*)d_ws;
  size_t off = 0;
  auto alloc = [&](size_t bytes) -> void* {
    off = (off + 255) & ~(size_t)255;
    void* p = ws + off;
    off += bytes;
    return p;
  };
  float* logits = (float*)alloc((size_t)EE * NTOK * 4);
  float* smax = (float*)alloc(64 * 4);
  float* ssum = (float*)alloc(64 * 4);
  int* sidx = (int*)alloc((size_t)EE * KSEL * 4);
  float* sval = (float*)alloc((size_t)EE * KSEL * 4);
  short* W1T = (short*)alloc((size_t)EE * ESS * DD * 2);
  short* W2T = (short*)alloc((size_t)EE * DD * ESS * 2);
  short* H = (short*)alloc((size_t)EE * KSEL * ESS * 2);

  hipMemsetAsync(d_out, 0, (size_t)out_size * sizeof(float), stream);
  // lin1 [D][E*ES] -> W1T [E*ES][D]
  k_transpose<<<dim3(64, 16, 1), 256, 0, stream>>>(lin1, W1T, DD, EE * ESS);
  // lin2 [E][ES][D] -> W2T [E][D][ES]
  k_transpose<<<dim3(16, 4, 16), 256, 0, stream>>>(lin2, W2T, ESS, DD);
  k_logits<<<NTOK / 4, 256, 0, stream>>>(x, gate, logits);
  k_stats<<<EE, 256, 0, stream>>>(logits, smax, ssum);
  k_select<<<EE, 256, 0, stream>>>(logits, smax, ssum, sidx, sval);
  k_gemm1<<<dim3(KSEL / 128, EE), 256, 0, stream>>>(x, W1T, sidx, sval, H);
  k_gemm2<<<dim3(KSEL / 128, DD / 256, EE), 256, 0, stream>>>(H, W2T, sidx, z);
}

// Round 2
// 468.186 us; speedup vs baseline: 1.1851x; 1.1851x over previous
//
#include <hip/hip_runtime.h>
#include <hip/hip_bf16.h>

#define BB 8
#define CC 4096
#define DD 1024
#define EE 16
#define ESS 256
#define KSEL 4096
#define NTOK (BB*CC)

typedef short bf16x8 __attribute__((ext_vector_type(8)));
typedef float f32x4 __attribute__((ext_vector_type(4)));

__device__ __forceinline__ short f2bf(float f) {
  unsigned u = __float_as_uint(f);
  u += 0x7FFFu + ((u >> 16) & 1u);
  return (short)(u >> 16);
}
__device__ __forceinline__ float bf2f(short s) {
  return __uint_as_float(((unsigned)(unsigned short)s) << 16);
}

// ---------------- K1: xsum + logits + x->bf16 conversion ----------------
__global__ void k_logits(const float* __restrict__ x, const float* __restrict__ gate,
                         float* __restrict__ logits, short* __restrict__ xb) {
  int wid = threadIdx.x >> 6, lane = threadIdx.x & 63;
  int t = blockIdx.x * 4 + wid;
  const float4* xr = reinterpret_cast<const float4*>(x + (size_t)t * DD);
  short4* xw = reinterpret_cast<short4*>(xb + (size_t)t * DD);
  float s = 0.f;
#pragma unroll
  for (int i = 0; i < 4; ++i) {
    float4 v = xr[lane + 64 * i];
    s += v.x + v.y + v.z + v.w;
    short4 p;
    p.x = f2bf(v.x); p.y = f2bf(v.y); p.z = f2bf(v.z); p.w = f2bf(v.w);
    xw[lane + 64 * i] = p;
  }
#pragma unroll
  for (int off = 32; off; off >>= 1) s += __shfl_xor(s, off);
  if (lane < EE) {
    int c = t & (CC - 1);
    logits[(size_t)lane * NTOK + t] = s * gate[c * EE + lane];
  }
}

// ---------------- K2: per-expert max + sumexp ----------------
__global__ void k_stats(const float* __restrict__ logits, float* __restrict__ smax,
                        float* __restrict__ ssum) {
  int e = blockIdx.x;
  const float* L = logits + (size_t)e * NTOK;
  __shared__ float red[1024];
  float m = -3.4e38f;
  for (int t = threadIdx.x; t < NTOK; t += 1024) m = fmaxf(m, L[t]);
  red[threadIdx.x] = m; __syncthreads();
  for (int s2 = 512; s2; s2 >>= 1) {
    if (threadIdx.x < s2) red[threadIdx.x] = fmaxf(red[threadIdx.x], red[threadIdx.x + s2]);
    __syncthreads();
  }
  m = red[0]; __syncthreads();
  float s = 0.f;
  for (int t = threadIdx.x; t < NTOK; t += 1024) s += expf(L[t] - m);
  red[threadIdx.x] = s; __syncthreads();
  for (int s2 = 512; s2; s2 >>= 1) {
    if (threadIdx.x < s2) red[threadIdx.x] += red[threadIdx.x + s2];
    __syncthreads();
  }
  if (threadIdx.x == 0) { smax[e] = m; ssum[e] = red[0]; }
}

// ---------------- K3: radix top-k select + ordered compaction + inverse map ----------------
__global__ void k_select(const float* __restrict__ logits, const float* __restrict__ smax,
                         const float* __restrict__ ssum, int* __restrict__ sel_idx,
                         float* __restrict__ sel_val, int* __restrict__ inv) {
  int e = blockIdx.x;
  const float* L = logits + (size_t)e * NTOK;
  __shared__ unsigned hist[256];
  __shared__ unsigned sh_prefix, sh_kth, sh_ngt;
  __shared__ unsigned wtg[16], wtq[16];
  __shared__ unsigned base_gt, base_eq;

  unsigned prefix = 0, kth = KSEL, n_gt = 0;
  for (int pass = 3; pass >= 0; --pass) {
    if (threadIdx.x < 256) hist[threadIdx.x] = 0;
    __syncthreads();
    unsigned shift = pass * 8;
    unsigned pmask = (pass == 3) ? 0u : (0xFFFFFFFFu << ((pass + 1) * 8));
    for (int t = threadIdx.x; t < NTOK; t += 1024) {
      unsigned u = __float_as_uint(L[t]);
      unsigned key = (u & 0x80000000u) ? ~u : (u | 0x80000000u);
      if ((key & pmask) == prefix) atomicAdd(&hist[(key >> shift) & 255], 1u);
    }
    __syncthreads();
    if (threadIdx.x == 0) {
      unsigned cum = 0; int d = 255;
      for (; d >= 0; --d) {
        if (cum + hist[d] >= kth) break;
        cum += hist[d];
      }
      sh_ngt = n_gt + cum;
      sh_kth = kth - cum;
      sh_prefix = prefix | ((unsigned)d << shift);
    }
    __syncthreads();
    prefix = sh_prefix; kth = sh_kth; n_gt = sh_ngt;
    __syncthreads();
  }
  unsigned tau = prefix;
  unsigned n_tie = KSEL - n_gt;
  float mx = smax[e], sm = ssum[e];

  if (threadIdx.x == 0) { base_gt = 0; base_eq = 0; }
  __syncthreads();
  int wid = threadIdx.x >> 6, lane = threadIdx.x & 63;
  for (int t0 = 0; t0 < NTOK; t0 += 1024) {
    int t = t0 + threadIdx.x;
    float lv = L[t];
    unsigned u = __float_as_uint(lv);
    unsigned key = (u & 0x80000000u) ? ~u : (u | 0x80000000u);
    bool g = key > tau, q = key == tau;
    unsigned long long bg = __ballot(g), bq = __ballot(q);
    unsigned long long lm = (1ull << lane) - 1ull;
    unsigned pg = __popcll(bg & lm), pq = __popcll(bq & lm);
    if (lane == 63) { wtg[wid] = pg + (g ? 1u : 0u); wtq[wid] = pq + (q ? 1u : 0u); }
    __syncthreads();
    unsigned og = base_gt, oq = base_eq;
    for (int w2 = 0; w2 < wid; ++w2) { og += wtg[w2]; oq += wtq[w2]; }
    unsigned slot = 0xFFFFFFFFu;
    if (g) slot = og + pg;
    else if (q) {
      unsigned r = oq + pq;
      if (r < n_tie) slot = n_gt + r;
    }
    if (slot != 0xFFFFFFFFu) {
      sel_idx[(size_t)e * KSEL + slot] = t;
      sel_val[(size_t)e * KSEL + slot] = expf(lv - mx) / sm;
      inv[(size_t)t * EE + e] = e * KSEL + (int)slot;
    }
    __syncthreads();
    if (threadIdx.x == 0) {
      unsigned sg = 0, sq = 0;
      for (int w2 = 0; w2 < 16; ++w2) { sg += wtg[w2]; sq += wtq[w2]; }
      base_gt += sg; base_eq += sq;
    }
    __syncthreads();
  }
}

// ---------------- transpose: src [batch][R][C] f32 -> dst [batch][C][R] bf16 ----------------
__global__ void k_transpose(const float* __restrict__ src, short* __restrict__ dst,
                            int R, int C) {
  __shared__ float tile[64][65];
  int c0 = blockIdx.x * 64, r0 = blockIdx.y * 64, b = blockIdx.z;
  const float* S = src + (size_t)b * R * C;
  short* Dp = dst + (size_t)b * R * C;
  int tx = threadIdx.x & 63, ty = threadIdx.x >> 6;
#pragma unroll
  for (int i = 0; i < 16; ++i) {
    int r = ty + 4 * i;
    tile[r][tx] = S[(size_t)(r0 + r) * C + c0 + tx];
  }
  __syncthreads();
#pragma unroll
  for (int i = 0; i < 16; ++i) {
    int cR = ty + 4 * i;
    Dp[(size_t)(c0 + cR) * R + r0 + tx] = f2bf(tile[tx][cR]);
  }
}

// ---------------- GEMM1: H[e][m][s] = bf16( relu( Xg[e] @ W1[e] ) * val[e][m] ) ----------------
// BM=128 BN=256 BK=64, 4 waves 2x2, 16x16x32 bf16 MFMA, XOR-swizzled LDS
__global__ __launch_bounds__(256, 3) void k_gemm1(
    const short* __restrict__ xb, const short* __restrict__ W1T,
    const int* __restrict__ sel_idx, const float* __restrict__ sel_val,
    short* __restrict__ H) {
  int e = blockIdx.y, m0 = blockIdx.x * 128;
  __shared__ bf16x8 As8[128 * 8];   // 16 KB
  __shared__ bf16x8 Bs8[256 * 8];   // 32 KB
  int tid = threadIdx.x, lane = tid & 63, wid = tid >> 6;
  int wr = wid >> 1, wc = wid & 1;
  const int* idxE = sel_idx + (size_t)e * KSEL;
  f32x4 acc[4][8] = {};

  int ar = tid >> 1, ah = tid & 1;
  int tokenA = idxE[m0 + ar];
  const short* aSrc = xb + (size_t)tokenA * DD;

  for (int kt = 0; kt < DD / 64; ++kt) {
    // stage A (bf16 gather, direct uint4 copy)
#pragma unroll
    for (int j = 0; j < 4; ++j) {
      int seg = ah * 4 + j;
      uint4 v = *reinterpret_cast<const uint4*>(aSrc + kt * 64 + seg * 8);
      reinterpret_cast<uint4*>(As8)[ar * 8 + (seg ^ (ar & 7))] = v;
    }
    // stage B from pre-transposed W1T[e][s][d]
#pragma unroll
    for (int j = 0; j < 8; ++j) {
      int seg_id = tid + 256 * j;
      int row = seg_id >> 3, s8 = seg_id & 7;
      uint4 v = *reinterpret_cast<const uint4*>(W1T + ((size_t)(e * ESS + row) * DD + kt * 64) + s8 * 8);
      reinterpret_cast<uint4*>(Bs8)[row * 8 + (s8 ^ (row & 7))] = v;
    }
    __syncthreads();
    bf16x8 af[4][2];
#pragma unroll
    for (int mg = 0; mg < 4; ++mg)
#pragma unroll
      for (int h = 0; h < 2; ++h) {
        int row = wr * 64 + mg * 16 + (lane & 15);
        int seg = h * 4 + (lane >> 4);
        af[mg][h] = As8[row * 8 + (seg ^ (row & 7))];
      }
#pragma unroll
    for (int ng = 0; ng < 8; ++ng) {
      bf16x8 bfr[2];
#pragma unroll
      for (int h = 0; h < 2; ++h) {
        int row = wc * 128 + ng * 16 + (lane & 15);
        int seg = h * 4 + (lane >> 4);
        bfr[h] = Bs8[row * 8 + (seg ^ (row & 7))];
      }
#pragma unroll
      for (int mg = 0; mg < 4; ++mg) {
        acc[mg][ng] = __builtin_amdgcn_mfma_f32_16x16x32_bf16(af[mg][0], bfr[0], acc[mg][ng], 0, 0, 0);
        acc[mg][ng] = __builtin_amdgcn_mfma_f32_16x16x32_bf16(af[mg][1], bfr[1], acc[mg][ng], 0, 0, 0);
      }
    }
    __syncthreads();
  }
#pragma unroll
  for (int mg = 0; mg < 4; ++mg) {
#pragma unroll
    for (int r = 0; r < 4; ++r) {
      int ml = wr * 64 + mg * 16 + (lane >> 4) * 4 + r;
      float v = sel_val[(size_t)e * KSEL + m0 + ml];
#pragma unroll
      for (int ng = 0; ng < 8; ++ng) {
        float o = fmaxf(acc[mg][ng][r], 0.f) * v;
        H[((size_t)(e * KSEL + m0 + ml)) * ESS + wc * 128 + ng * 16 + (lane & 15)] = f2bf(o);
      }
    }
  }
}

// ---------------- GEMM2: out[e*K+slot][d] = bf16(H[e] @ W2[e])  (or atomic fallback) ----------------
template <int COMBINE>
__global__ __launch_bounds__(256, 3) void k_gemm2(
    const short* __restrict__ H, const short* __restrict__ W2T,
    const int* __restrict__ sel_idx, float* __restrict__ z, short* __restrict__ out) {
  int e = blockIdx.z, m0 = blockIdx.x * 128, n0 = blockIdx.y * 256;
  __shared__ bf16x8 As8[128 * 8];
  __shared__ bf16x8 Bs8[256 * 8];
  int tid = threadIdx.x, lane = tid & 63, wid = tid >> 6;
  int wr = wid >> 1, wc = wid & 1;
  f32x4 acc[4][8] = {};

  for (int kt = 0; kt < ESS / 64; ++kt) {
#pragma unroll
    for (int j = 0; j < 4; ++j) {
      int seg_id = tid + 256 * j;
      int row = seg_id >> 3, s8 = seg_id & 7;
      uint4 v = *reinterpret_cast<const uint4*>(H + ((size_t)(e * KSEL + m0 + row) * ESS + kt * 64) + s8 * 8);
      reinterpret_cast<uint4*>(As8)[row * 8 + (s8 ^ (row & 7))] = v;
    }
#pragma unroll
    for (int j = 0; j < 8; ++j) {
      int seg_id = tid + 256 * j;
      int row = seg_id >> 3, s8 = seg_id & 7;
      uint4 v = *reinterpret_cast<const uint4*>(W2T + ((size_t)(e * DD + n0 + row) * ESS + kt * 64) + s8 * 8);
      reinterpret_cast<uint4*>(Bs8)[row * 8 + (s8 ^ (row & 7))] = v;
    }
    __syncthreads();
    bf16x8 af[4][2];
#pragma unroll
    for (int mg = 0; mg < 4; ++mg)
#pragma unroll
      for (int h = 0; h < 2; ++h) {
        int row = wr * 64 + mg * 16 + (lane & 15);
        int seg = h * 4 + (lane >> 4);
        af[mg][h] = As8[row * 8 + (seg ^ (row & 7))];
      }
#pragma unroll
    for (int ng = 0; ng < 8; ++ng) {
      bf16x8 bfr[2];
#pragma unroll
      for (int h = 0; h < 2; ++h) {
        int row = wc * 128 + ng * 16 + (lane & 15);
        int seg = h * 4 + (lane >> 4);
        bfr[h] = Bs8[row * 8 + (seg ^ (row & 7))];
      }
#pragma unroll
      for (int mg = 0; mg < 4; ++mg) {
        acc[mg][ng] = __builtin_amdgcn_mfma_f32_16x16x32_bf16(af[mg][0], bfr[0], acc[mg][ng], 0, 0, 0);
        acc[mg][ng] = __builtin_amdgcn_mfma_f32_16x16x32_bf16(af[mg][1], bfr[1], acc[mg][ng], 0, 0, 0);
      }
    }
    __syncthreads();
  }
#pragma unroll
  for (int mg = 0; mg < 4; ++mg) {
#pragma unroll
    for (int r = 0; r < 4; ++r) {
      int ml = wr * 64 + mg * 16 + (lane >> 4) * 4 + r;
      if (COMBINE) {
        short* orow = out + ((size_t)(e * KSEL + m0 + ml)) * DD + n0 + wc * 128 + (lane & 15);
#pragma unroll
        for (int ng = 0; ng < 8; ++ng) orow[ng * 16] = f2bf(acc[mg][ng][r]);
      } else {
        int token = sel_idx[(size_t)e * KSEL + m0 + ml];
        float* zr = z + (size_t)token * DD + n0 + wc * 128 + (lane & 15);
#pragma unroll
        for (int ng = 0; ng < 8; ++ng) atomicAdd(zr + ng * 16, acc[mg][ng][r]);
      }
    }
  }
}

// ---------------- combine: z[t][d] = sum over experts of out[inv[t][e]][d] ----------------
__global__ void k_combine(const short* __restrict__ out, const int* __restrict__ inv,
                          float* __restrict__ z) {
  int wid = threadIdx.x >> 6, lane = threadIdx.x & 63;
  int t = blockIdx.x * 4 + wid;
  const int* iv = inv + (size_t)t * EE;
  float acc[16] = {};
#pragma unroll 1
  for (int e = 0; e < EE; ++e) {
    int g = iv[e];
    if (g < 0) continue;
    const uint4* rp = reinterpret_cast<const uint4*>(out + (size_t)g * DD + lane * 16);
    uint4 v0 = rp[0], v1 = rp[1];
    const short* s0 = reinterpret_cast<const short*>(&v0);
    const short* s1 = reinterpret_cast<const short*>(&v1);
#pragma unroll
    for (int i = 0; i < 8; ++i) acc[i] += bf2f(s0[i]);
#pragma unroll
    for (int i = 0; i < 8; ++i) acc[8 + i] += bf2f(s1[i]);
  }
  float4* zw = reinterpret_cast<float4*>(z + (size_t)t * DD + lane * 16);
#pragma unroll
  for (int i = 0; i < 4; ++i) {
    float4 o; o.x = acc[4 * i]; o.y = acc[4 * i + 1]; o.z = acc[4 * i + 2]; o.w = acc[4 * i + 3];
    zw[i] = o;
  }
}

extern "C" void kernel_launch(void* const* d_in, const int* in_sizes, int n_in,
                              void* d_out, int out_size, void* d_ws, size_t ws_size,
                              hipStream_t stream) {
  (void)in_sizes; (void)n_in;
  const float* x = (const float*)d_in[0];
  const float* gate = (const float*)d_in[1];
  const float* lin1 = (const float*)d_in[2];
  const float* lin2 = (const float*)d_in[3];
  float* z = (float*)d_out;

  char* ws = (char*)d_ws;
  size_t off = 0;
  auto alloc = [&](size_t bytes) -> void* {
    off = (off + 255) & ~(size_t)255;
    void* p = ws + off;
    off += bytes;
    return p;
  };
  float* logits = (float*)alloc((size_t)EE * NTOK * 4);
  float* smax = (float*)alloc(64 * 4);
  float* ssum = (float*)alloc(64 * 4);
  int* sidx = (int*)alloc((size_t)EE * KSEL * 4);
  float* sval = (float*)alloc((size_t)EE * KSEL * 4);
  int* inv = (int*)alloc((size_t)NTOK * EE * 4);
  short* W1T = (short*)alloc((size_t)EE * ESS * DD * 2);
  short* W2T = (short*)alloc((size_t)EE * DD * ESS * 2);
  short* H = (short*)alloc((size_t)EE * KSEL * ESS * 2);
  short* xb = (short*)alloc((size_t)NTOK * DD * 2);
  size_t out_bytes = (size_t)EE * KSEL * DD * 2;
  bool combine = (off + 256 + out_bytes) <= ws_size;
  short* outbuf = combine ? (short*)alloc(out_bytes) : nullptr;

  // weight transposes
  k_transpose<<<dim3(64, 16, 1), 256, 0, stream>>>(lin1, W1T, DD, EE * ESS);
  k_transpose<<<dim3(16, 4, 16), 256, 0, stream>>>(lin2, W2T, ESS, DD);
  // gating
  k_logits<<<NTOK / 4, 256, 0, stream>>>(x, gate, logits, xb);
  k_stats<<<EE, 1024, 0, stream>>>(logits, smax, ssum);
  hipMemsetAsync(inv, 0xFF, (size_t)NTOK * EE * 4, stream);
  k_select<<<EE, 1024, 0, stream>>>(logits, smax, ssum, sidx, sval, inv);
  // expert FF
  k_gemm1<<<dim3(KSEL / 128, EE), 256, 0, stream>>>(xb, W1T, sidx, sval, H);
  if (combine) {
    k_gemm2<1><<<dim3(KSEL / 128, DD / 256, EE), 256, 0, stream>>>(H, W2T, sidx, z, outbuf);
    k_combine<<<NTOK / 4, 256, 0, stream>>>(outbuf, inv, z);
  } else {
    hipMemsetAsync(d_out, 0, (size_t)out_size * sizeof(float), stream);
    k_gemm2<0><<<dim3(KSEL / 128, DD / 256, EE), 256, 0, stream>>>(H, W2T, sidx, z, nullptr);
  }
}

// Round 3
// 351.443 us; speedup vs baseline: 1.5788x; 1.3322x over previous
//
#include <hip/hip_runtime.h>
#include <hip/hip_bf16.h>

#define BB 8
#define CC 4096
#define DD 1024
#define EE 16
#define ESS 256
#define KSEL 4096
#define NTOK (BB*CC)

typedef short bf16x8 __attribute__((ext_vector_type(8)));
typedef float f32x4 __attribute__((ext_vector_type(4)));

__device__ __forceinline__ short f2bf(float f) {
  unsigned u = __float_as_uint(f);
  u += 0x7FFFu + ((u >> 16) & 1u);
  return (short)(u >> 16);
}
__device__ __forceinline__ float bf2f(short s) {
  return __uint_as_float(((unsigned)(unsigned short)s) << 16);
}

#define ASG __attribute__((address_space(1)))
#define ASL __attribute__((address_space(3)))
__device__ __forceinline__ void gl_lds16(void* l, const void* g) {
  __builtin_amdgcn_global_load_lds((ASG const unsigned*)g, (ASL unsigned*)l, 16, 0, 0);
}

// ---------------- K1: xsum + logits + x->bf16 conversion ----------------
__global__ void k_logits(const float* __restrict__ x, const float* __restrict__ gate,
                         float* __restrict__ logits, short* __restrict__ xb) {
  int wid = threadIdx.x >> 6, lane = threadIdx.x & 63;
  int t = blockIdx.x * 4 + wid;
  const float4* xr = reinterpret_cast<const float4*>(x + (size_t)t * DD);
  short4* xw = reinterpret_cast<short4*>(xb + (size_t)t * DD);
  float s = 0.f;
#pragma unroll
  for (int i = 0; i < 4; ++i) {
    float4 v = xr[lane + 64 * i];
    s += v.x + v.y + v.z + v.w;
    short4 p;
    p.x = f2bf(v.x); p.y = f2bf(v.y); p.z = f2bf(v.z); p.w = f2bf(v.w);
    xw[lane + 64 * i] = p;
  }
#pragma unroll
  for (int off = 32; off; off >>= 1) s += __shfl_xor(s, off);
  if (lane < EE) {
    int c = t & (CC - 1);
    logits[(size_t)lane * NTOK + t] = s * gate[c * EE + lane];
  }
}

// ---------------- K3: radix top-k select (stats folded in) + ordered compaction ----------------
__global__ __launch_bounds__(1024) void k_select(
    const float* __restrict__ logits, int* __restrict__ sel_idx,
    float* __restrict__ sel_val, int* __restrict__ inv) {
  int e = blockIdx.x;
  const float* L = logits + (size_t)e * NTOK;
  __shared__ unsigned whist[16][256];
  __shared__ unsigned chist[256];
  __shared__ float red[1024];
  __shared__ float sh_mx, sh_sm;
  __shared__ unsigned sh_prefix, sh_kth, sh_ngt;
  __shared__ unsigned wtg[16], wtq[16];
  __shared__ unsigned base_gt, base_eq;
  int tid = threadIdx.x, wid = tid >> 6, lane = tid & 63;

  unsigned prefix = 0, kth = KSEL, n_gt = 0;
  float mloc = -3.4e38f, sloc = 0.f;
  for (int pass = 3; pass >= 0; --pass) {
    for (int i = tid; i < 16 * 256; i += 1024) ((unsigned*)whist)[i] = 0;
    __syncthreads();
    float mxl = (pass == 2) ? sh_mx : 0.f;
    unsigned shift = pass * 8;
    unsigned pmask = (pass == 3) ? 0u : (0xFFFFFFFFu << ((pass + 1) * 8));
    for (int t = tid; t < NTOK; t += 1024) {
      float lv = L[t];
      unsigned u = __float_as_uint(lv);
      unsigned key = (u & 0x80000000u) ? ~u : (u | 0x80000000u);
      if (pass == 3) mloc = fmaxf(mloc, lv);
      if (pass == 2) sloc += expf(lv - mxl);
      if ((key & pmask) == prefix) atomicAdd(&whist[wid][(key >> shift) & 255], 1u);
    }
    __syncthreads();
    if (tid < 256) {
      unsigned s = 0;
#pragma unroll
      for (int w = 0; w < 16; ++w) s += whist[w][tid];
      chist[tid] = s;
    }
    if (pass == 3) red[tid] = mloc;
    if (pass == 2) red[tid] = sloc;
    __syncthreads();
    if (pass == 3) {
      for (int s2 = 512; s2; s2 >>= 1) {
        if (tid < s2) red[tid] = fmaxf(red[tid], red[tid + s2]);
        __syncthreads();
      }
      if (tid == 0) sh_mx = red[0];
    }
    if (pass == 2) {
      for (int s2 = 512; s2; s2 >>= 1) {
        if (tid < s2) red[tid] += red[tid + s2];
        __syncthreads();
      }
      if (tid == 0) sh_sm = red[0];
    }
    if (tid == 0) {
      unsigned cum = 0; int d = 255;
      for (; d >= 0; --d) {
        if (cum + chist[d] >= kth) break;
        cum += chist[d];
      }
      sh_ngt = n_gt + cum;
      sh_kth = kth - cum;
      sh_prefix = prefix | ((unsigned)d << shift);
    }
    __syncthreads();
    prefix = sh_prefix; kth = sh_kth; n_gt = sh_ngt;
    __syncthreads();
  }
  unsigned tau = prefix;
  unsigned n_tie = KSEL - n_gt;
  float mx = sh_mx, sm = sh_sm;

  if (tid == 0) { base_gt = 0; base_eq = 0; }
  __syncthreads();
  for (int t0 = 0; t0 < NTOK; t0 += 1024) {
    int t = t0 + tid;
    float lv = L[t];
    unsigned u = __float_as_uint(lv);
    unsigned key = (u & 0x80000000u) ? ~u : (u | 0x80000000u);
    bool g = key > tau, q = key == tau;
    unsigned long long bg = __ballot(g), bq = __ballot(q);
    unsigned long long lm = (1ull << lane) - 1ull;
    unsigned pg = __popcll(bg & lm), pq = __popcll(bq & lm);
    if (lane == 63) { wtg[wid] = pg + (g ? 1u : 0u); wtq[wid] = pq + (q ? 1u : 0u); }
    __syncthreads();
    unsigned og = base_gt, oq = base_eq;
    for (int w2 = 0; w2 < wid; ++w2) { og += wtg[w2]; oq += wtq[w2]; }
    unsigned slot = 0xFFFFFFFFu;
    if (g) slot = og + pg;
    else if (q) {
      unsigned r = oq + pq;
      if (r < n_tie) slot = n_gt + r;
    }
    if (slot != 0xFFFFFFFFu) {
      sel_idx[(size_t)e * KSEL + slot] = t;
      sel_val[(size_t)e * KSEL + slot] = expf(lv - mx) / sm;
      inv[(size_t)t * EE + e] = e * KSEL + (int)slot;
    }
    __syncthreads();
    if (tid == 0) {
      unsigned sg = 0, sq = 0;
#pragma unroll
      for (int w2 = 0; w2 < 16; ++w2) { sg += wtg[w2]; sq += wtq[w2]; }
      base_gt += sg; base_eq += sq;
    }
    __syncthreads();
  }
}

// ---------------- transpose: src [batch][R][C] f32 -> dst [batch][C][R] bf16 ----------------
__global__ void k_transpose(const float* __restrict__ src, short* __restrict__ dst,
                            int R, int C) {
  __shared__ float tile[64][65];
  int c0 = blockIdx.x * 64, r0 = blockIdx.y * 64, b = blockIdx.z;
  const float* S = src + (size_t)b * R * C;
  short* Dp = dst + (size_t)b * R * C;
  int tx = threadIdx.x & 63, ty = threadIdx.x >> 6;
#pragma unroll
  for (int i = 0; i < 16; ++i) {
    int r = ty + 4 * i;
    tile[r][tx] = S[(size_t)(r0 + r) * C + c0 + tx];
  }
  __syncthreads();
#pragma unroll
  for (int i = 0; i < 16; ++i) {
    int cR = ty + 4 * i;
    Dp[(size_t)(c0 + cR) * R + r0 + tx] = f2bf(tile[tx][cR]);
  }
}

// ---------------- GEMM1: H[e][m][s] = bf16( relu( Xg[e] @ W1[e] ) * val[e][m] ) ----------------
// BM=128 BN=256 BK=64, 8 waves 2x4 (64x64 each), global_load_lds staging, swizzle-on-source
__global__ __launch_bounds__(512, 4) void k_gemm1(
    const short* __restrict__ xb, const short* __restrict__ W1T,
    const int* __restrict__ sel_idx, const float* __restrict__ sel_val,
    short* __restrict__ H) {
  int bid = blockIdx.x;
  int m0 = ((bid >> 3) & 31) * 128;
  int e = (bid & 7) + ((bid >> 8) << 3);
  __shared__ bf16x8 As8[128 * 8];   // 16 KB
  __shared__ bf16x8 Bs8[256 * 8];   // 32 KB
  int tid = threadIdx.x, lane = tid & 63, wid = tid >> 6;
  int wr = wid >> 2, wc = wid & 3;
  const int* idxE = sel_idx + (size_t)e * KSEL;
  f32x4 acc[4][4] = {};

  int rowA = tid >> 3, sA = tid & 7;
  int xk = rowA & 7;
  const short* aSrc0 = xb + (size_t)idxE[m0 + rowA] * DD + (sA ^ xk) * 8;
  const short* aSrc1 = xb + (size_t)idxE[m0 + rowA + 64] * DD + (sA ^ xk) * 8;
  const short* wBase = W1T + (size_t)e * ESS * DD + (size_t)rowA * DD + (sA ^ xk) * 8;

  for (int kt = 0; kt < DD / 64; ++kt) {
    int kofs = kt * 64;
    gl_lds16(&As8[tid], aSrc0 + kofs);
    gl_lds16(&As8[512 + tid], aSrc1 + kofs);
#pragma unroll
    for (int j = 0; j < 4; ++j)
      gl_lds16(&Bs8[j * 512 + tid], wBase + (size_t)(64 * j) * DD + kofs);
    __syncthreads();
    bf16x8 af[4][2];
#pragma unroll
    for (int mg = 0; mg < 4; ++mg) {
      int row = wr * 64 + mg * 16 + (lane & 15);
#pragma unroll
      for (int h = 0; h < 2; ++h) {
        int seg = h * 4 + (lane >> 4);
        af[mg][h] = As8[row * 8 + (seg ^ (row & 7))];
      }
    }
#pragma unroll
    for (int ng = 0; ng < 4; ++ng) {
      int rowb = wc * 64 + ng * 16 + (lane & 15);
      bf16x8 b0 = Bs8[rowb * 8 + (((lane >> 4) + 0) ^ (rowb & 7))];
      bf16x8 b1 = Bs8[rowb * 8 + (((lane >> 4) + 4) ^ (rowb & 7))];
#pragma unroll
      for (int mg = 0; mg < 4; ++mg) {
        acc[mg][ng] = __builtin_amdgcn_mfma_f32_16x16x32_bf16(af[mg][0], b0, acc[mg][ng], 0, 0, 0);
        acc[mg][ng] = __builtin_amdgcn_mfma_f32_16x16x32_bf16(af[mg][1], b1, acc[mg][ng], 0, 0, 0);
      }
    }
    __syncthreads();
  }
#pragma unroll
  for (int mg = 0; mg < 4; ++mg) {
#pragma unroll
    for (int r = 0; r < 4; ++r) {
      int ml = wr * 64 + mg * 16 + (lane >> 4) * 4 + r;
      float v = sel_val[(size_t)e * KSEL + m0 + ml];
#pragma unroll
      for (int ng = 0; ng < 4; ++ng) {
        float o = fmaxf(acc[mg][ng][r], 0.f) * v;
        H[((size_t)(e * KSEL + m0 + ml)) * ESS + wc * 64 + ng * 16 + (lane & 15)] = f2bf(o);
      }
    }
  }
}

// ---------------- GEMM2: out[e*K+slot][d] = bf16(H[e] @ W2[e])  (or atomic fallback) ----------------
template <int COMBINE>
__global__ __launch_bounds__(512, 4) void k_gemm2(
    const short* __restrict__ H, const short* __restrict__ W2T,
    const int* __restrict__ sel_idx, float* __restrict__ z, short* __restrict__ out) {
  int bid = blockIdx.x;
  int p = (bid & 7) + ((bid >> 8) << 3);   // 64 panels: (n,e)
  int m0 = ((bid >> 3) & 31) * 128;
  int n0 = (p & 3) * 256;
  int e = p >> 2;
  __shared__ bf16x8 As8[128 * 8];
  __shared__ bf16x8 Bs8[256 * 8];
  int tid = threadIdx.x, lane = tid & 63, wid = tid >> 6;
  int wr = wid >> 2, wc = wid & 3;
  f32x4 acc[4][4] = {};

  int rowA = tid >> 3, sA = tid & 7;
  int xk = rowA & 7;
  const short* hBase = H + (size_t)(e * KSEL + m0 + rowA) * ESS + (sA ^ xk) * 8;
  const short* w2Base = W2T + (size_t)(e * DD + n0 + rowA) * ESS + (sA ^ xk) * 8;

  for (int kt = 0; kt < ESS / 64; ++kt) {
    int kofs = kt * 64;
    gl_lds16(&As8[tid], hBase + kofs);
    gl_lds16(&As8[512 + tid], hBase + (size_t)64 * ESS + kofs);
#pragma unroll
    for (int j = 0; j < 4; ++j)
      gl_lds16(&Bs8[j * 512 + tid], w2Base + (size_t)(64 * j) * ESS + kofs);
    __syncthreads();
    bf16x8 af[4][2];
#pragma unroll
    for (int mg = 0; mg < 4; ++mg) {
      int row = wr * 64 + mg * 16 + (lane & 15);
#pragma unroll
      for (int h = 0; h < 2; ++h) {
        int seg = h * 4 + (lane >> 4);
        af[mg][h] = As8[row * 8 + (seg ^ (row & 7))];
      }
    }
#pragma unroll
    for (int ng = 0; ng < 4; ++ng) {
      int rowb = wc * 64 + ng * 16 + (lane & 15);
      bf16x8 b0 = Bs8[rowb * 8 + (((lane >> 4) + 0) ^ (rowb & 7))];
      bf16x8 b1 = Bs8[rowb * 8 + (((lane >> 4) + 4) ^ (rowb & 7))];
#pragma unroll
      for (int mg = 0; mg < 4; ++mg) {
        acc[mg][ng] = __builtin_amdgcn_mfma_f32_16x16x32_bf16(af[mg][0], b0, acc[mg][ng], 0, 0, 0);
        acc[mg][ng] = __builtin_amdgcn_mfma_f32_16x16x32_bf16(af[mg][1], b1, acc[mg][ng], 0, 0, 0);
      }
    }
    __syncthreads();
  }
#pragma unroll
  for (int mg = 0; mg < 4; ++mg) {
#pragma unroll
    for (int r = 0; r < 4; ++r) {
      int ml = wr * 64 + mg * 16 + (lane >> 4) * 4 + r;
      if (COMBINE) {
        short* orow = out + ((size_t)(e * KSEL + m0 + ml)) * DD + n0 + wc * 64 + (lane & 15);
#pragma unroll
        for (int ng = 0; ng < 4; ++ng) orow[ng * 16] = f2bf(acc[mg][ng][r]);
      } else {
        int token = sel_idx[(size_t)e * KSEL + m0 + ml];
        float* zr = z + (size_t)token * DD + n0 + wc * 64 + (lane & 15);
#pragma unroll
        for (int ng = 0; ng < 4; ++ng) atomicAdd(zr + ng * 16, acc[mg][ng][r]);
      }
    }
  }
}

// ---------------- combine: z[t][d] = sum over experts of out[inv[t][e]][d] ----------------
__global__ void k_combine(const short* __restrict__ out, const int* __restrict__ inv,
                          float* __restrict__ z) {
  int wid = threadIdx.x >> 6, lane = threadIdx.x & 63;
  int t = blockIdx.x * 4 + wid;
  int g[16];
  const int4* iv4 = reinterpret_cast<const int4*>(inv + (size_t)t * EE);
#pragma unroll
  for (int q = 0; q < 4; ++q) {
    int4 v = iv4[q];
    g[4 * q] = v.x; g[4 * q + 1] = v.y; g[4 * q + 2] = v.z; g[4 * q + 3] = v.w;
  }
  float acc[16] = {};
#pragma unroll
  for (int e = 0; e < EE; ++e) {
    if (g[e] < 0) continue;
    const uint4* rp = reinterpret_cast<const uint4*>(out + (size_t)g[e] * DD + lane * 16);
    uint4 v0 = rp[0], v1 = rp[1];
    const short* s0 = reinterpret_cast<const short*>(&v0);
    const short* s1 = reinterpret_cast<const short*>(&v1);
#pragma unroll
    for (int i = 0; i < 8; ++i) acc[i] += bf2f(s0[i]);
#pragma unroll
    for (int i = 0; i < 8; ++i) acc[8 + i] += bf2f(s1[i]);
  }
  float4* zw = reinterpret_cast<float4*>(z + (size_t)t * DD + lane * 16);
#pragma unroll
  for (int i = 0; i < 4; ++i) {
    float4 o; o.x = acc[4 * i]; o.y = acc[4 * i + 1]; o.z = acc[4 * i + 2]; o.w = acc[4 * i + 3];
    zw[i] = o;
  }
}

extern "C" void kernel_launch(void* const* d_in, const int* in_sizes, int n_in,
                              void* d_out, int out_size, void* d_ws, size_t ws_size,
                              hipStream_t stream) {
  (void)in_sizes; (void)n_in;
  const float* x = (const float*)d_in[0];
  const float* gate = (const float*)d_in[1];
  const float* lin1 = (const float*)d_in[2];
  const float* lin2 = (const float*)d_in[3];
  float* z = (float*)d_out;

  char* ws = (char*)d_ws;
  size_t off = 0;
  auto alloc = [&](size_t bytes) -> void* {
    off = (off + 255) & ~(size_t)255;
    void* p = ws + off;
    off += bytes;
    return p;
  };
  float* logits = (float*)alloc((size_t)EE * NTOK * 4);
  int* sidx = (int*)alloc((size_t)EE * KSEL * 4);
  float* sval = (float*)alloc((size_t)EE * KSEL * 4);
  int* inv = (int*)alloc((size_t)NTOK * EE * 4);
  short* W1T = (short*)alloc((size_t)EE * ESS * DD * 2);
  short* W2T = (short*)alloc((size_t)EE * DD * ESS * 2);
  short* H = (short*)alloc((size_t)EE * KSEL * ESS * 2);
  short* xb = (short*)alloc((size_t)NTOK * DD * 2);
  size_t out_bytes = (size_t)EE * KSEL * DD * 2;
  bool combine = (off + 256 + out_bytes) <= ws_size;
  short* outbuf = combine ? (short*)alloc(out_bytes) : nullptr;

  // weight transposes
  k_transpose<<<dim3(64, 16, 1), 256, 0, stream>>>(lin1, W1T, DD, EE * ESS);
  k_transpose<<<dim3(16, 4, 16), 256, 0, stream>>>(lin2, W2T, ESS, DD);
  // gating
  k_logits<<<NTOK / 4, 256, 0, stream>>>(x, gate, logits, xb);
  hipMemsetAsync(inv, 0xFF, (size_t)NTOK * EE * 4, stream);
  k_select<<<EE, 1024, 0, stream>>>(logits, sidx, sval, inv);
  // expert FF
  k_gemm1<<<512, 512, 0, stream>>>(xb, W1T, sidx, sval, H);
  if (combine) {
    k_gemm2<1><<<2048, 512, 0, stream>>>(H, W2T, sidx, z, outbuf);
    k_combine<<<NTOK / 4, 256, 0, stream>>>(outbuf, inv, z);
  } else {
    hipMemsetAsync(d_out, 0, (size_t)out_size * sizeof(float), stream);
    k_gemm2<0><<<2048, 512, 0, stream>>>(H, W2T, sidx, z, nullptr);
  }
}